// Round 4
// baseline (391.997 us; speedup 1.0000x reference)
//
#include <hip/hip_runtime.h>
#include <hip/hip_bf16.h>

#define N_NODES 100000
#define N_EDGES 1000000
#define D 64

// ---- histogram: ONE packed 64-bit atomic per edge, 4 edges/thread --------
// bits [63:40] = edge count, bits [39:0] = fixed-point sum of (w + 8) * 2^20
// The atomic's RETURN gives this edge's rank within its dst row -> rank[]
// so the CSR fill needs NO atomics.
__global__ __launch_bounds__(256) void hist_kernel(
    const int* __restrict__ dst, const int* __restrict__ efeat,
    const float* __restrict__ edge_weight,
    unsigned long long* __restrict__ dc,
    unsigned char* __restrict__ rank) {
    int e0 = (blockIdx.x * 256 + threadIdx.x) * 4;
    if (e0 >= N_EDGES) return;                 // N_EDGES % 4 == 0
    int4 d4 = *(const int4*)(dst + e0);
    int4 t4 = *(const int4*)(efeat + e0);
    float w0 = edge_weight[t4.x - 1] * 10.0f;
    float w1 = edge_weight[t4.y - 1] * 10.0f;
    float w2 = edge_weight[t4.z - 1] * 10.0f;
    float w3 = edge_weight[t4.w - 1] * 10.0f;
    w0 = w0 > 0.0f ? w0 : 0.01f * w0;          // leaky_relu, slope 0.01
    w1 = w1 > 0.0f ? w1 : 0.01f * w1;
    w2 = w2 > 0.0f ? w2 : 0.01f * w2;
    w3 = w3 > 0.0f ? w3 : 0.01f * w3;
    unsigned long long f0 = (unsigned long long)__float2uint_rn((w0 + 8.0f) * 1048576.0f);
    unsigned long long f1 = (unsigned long long)__float2uint_rn((w1 + 8.0f) * 1048576.0f);
    unsigned long long f2 = (unsigned long long)__float2uint_rn((w2 + 8.0f) * 1048576.0f);
    unsigned long long f3 = (unsigned long long)__float2uint_rn((w3 + 8.0f) * 1048576.0f);
    unsigned long long o0 = atomicAdd(&dc[d4.x], (1ull << 40) | f0);
    unsigned long long o1 = atomicAdd(&dc[d4.y], (1ull << 40) | f1);
    unsigned long long o2 = atomicAdd(&dc[d4.z], (1ull << 40) | f2);
    unsigned long long o3 = atomicAdd(&dc[d4.w], (1ull << 40) | f3);
    uchar4 r;
    r.x = (unsigned char)(o0 >> 40);
    r.y = (unsigned char)(o1 >> 40);
    r.z = (unsigned char)(o2 >> 40);
    r.w = (unsigned char)(o3 >> 40);
    *(uchar4*)(rank + e0) = r;
}

// ---- fused: dc -> meta{row_start,cnt,norm}, CSR alloc, AND build g1 ------
__global__ __launch_bounds__(256) void alloc_prep_kernel(
    const unsigned long long* __restrict__ dc,
    const float* __restrict__ feats,
    int4* __restrict__ meta,
    int* __restrict__ total,
    __hip_bfloat16* __restrict__ g1) {
    __shared__ int lds[256];
    __shared__ float norm_s[256];
    __shared__ int base_s;
    const int tid = threadIdx.x;
    const int i = blockIdx.x * 256 + tid;
    int v = 0;
    float nv = 1.0f;
    if (i < N_NODES) {
        unsigned long long p = dc[i];
        v = (int)(p >> 40);
        float deg = (float)(p & ((1ull << 40) - 1)) * (1.0f / 1048576.0f)
                    - 8.0f * (float)v;
        deg = deg < 1.0f ? 1.0f : deg;
        nv = rsqrtf(deg);
    }
    norm_s[tid] = nv;
    lds[tid] = v;
    __syncthreads();
    for (int off = 1; off < 256; off <<= 1) {
        int add = (tid >= off) ? lds[tid - off] : 0;
        __syncthreads();
        lds[tid] += add;
        __syncthreads();
    }
    if (tid == 255) base_s = atomicAdd(total, lds[255]);
    __syncthreads();
    if (i < N_NODES) {
        int4 m;
        m.x = base_s + lds[tid] - v;       // row_start (block-excl + base)
        m.y = v;                           // cnt
        m.z = __float_as_int(nv);          // norm
        m.w = 0;
        meta[i] = m;
    }
    // ---- g1[n][k] = bf16(feats[n][k] * norm[n]) for this block's nodes ---
    const float4* f4 = (const float4*)feats;
    __hip_bfloat162* g1p = (__hip_bfloat162*)g1;
    const int base4 = blockIdx.x * 4096;   // 256 nodes * 16 float4/node
#pragma unroll
    for (int r = 0; r < 16; r++) {
        int li = r * 256 + tid;
        int gi = base4 + li;
        if (gi < N_NODES * 16) {
            float4 vv = f4[gi];
            float ns = norm_s[li >> 4];
            __hip_bfloat162 a, b;
            a.x = __float2bfloat16(vv.x * ns); a.y = __float2bfloat16(vv.y * ns);
            b.x = __float2bfloat16(vv.z * ns); b.y = __float2bfloat16(vv.w * ns);
            g1p[gi * 2]     = a;
            g1p[gi * 2 + 1] = b;
        }
    }
}

// ---- atomic-free CSR fill: pos = row_start[dst] + rank, 4 edges/thread ---
__global__ __launch_bounds__(256) void fill_kernel(
    const int* __restrict__ src, const int* __restrict__ dst,
    const unsigned char* __restrict__ rank,
    const int* __restrict__ meta_i,        // meta as int*, row_start at 4*d
    int* __restrict__ csr_src) {
    int e0 = (blockIdx.x * 256 + threadIdx.x) * 4;
    if (e0 >= N_EDGES) return;
    int4 d4 = *(const int4*)(dst + e0);
    uchar4 r4 = *(const uchar4*)(rank + e0);
    int4 s4 = *(const int4*)(src + e0);
    int p0 = meta_i[d4.x * 4] + r4.x;          // 4 independent random reads
    int p1 = meta_i[d4.y * 4] + r4.y;
    int p2 = meta_i[d4.z * 4] + r4.z;
    int p3 = meta_i[d4.w * 4] + r4.w;
    csr_src[p0] = s4.x;
    csr_src[p1] = s4.y;
    csr_src[p2] = s4.z;
    csr_src[p3] = s4.w;
}

// ---- plain GEMM for j=0: out[:,0:64] = feats @ W0 ----
__global__ __launch_bounds__(256) void gemm_kernel(
    const float* __restrict__ H,
    const float* __restrict__ W,
    float* __restrict__ out) {
    __shared__ float wt[D][D];
    __shared__ float ht[32][D];
    const int tid = threadIdx.x;
    const int node0 = blockIdx.x * 32;
    for (int i = tid; i < D * D; i += 256)
        ((float*)wt)[i] = W[i];
    for (int i = tid; i < 32 * D; i += 256) {
        int n = i >> 6;
        int k = i & 63;
        int node = node0 + n;
        ht[n][k] = (node < N_NODES) ? H[(size_t)node * D + k] : 0.0f;
    }
    __syncthreads();
    const int col = tid & 63;
    const int nb = tid >> 6;
    float acc[8];
#pragma unroll
    for (int r = 0; r < 8; r++) acc[r] = 0.0f;
    for (int k = 0; k < D; k++) {
        float wv = wt[k][col];
#pragma unroll
        for (int r = 0; r < 8; r++)
            acc[r] += ht[nb * 8 + r][k] * wv;
    }
#pragma unroll
    for (int r = 0; r < 8; r++) {
        int node = node0 + nb * 8 + r;
        if (node < N_NODES)
            out[(size_t)node * 192 + col] = acc[r];
    }
}

// ---- fused bf16 gather-sum + GEMM epilogue: dwordx2 gathers, node pairs --
// lane = (quarter q = lane>>4, feature-quad fp = lane&15). One gather instr
// = 4 edges (16 lanes x 8 B = one 128 B row). Each wave interleaves TWO
// nodes (n, n+8192): independent chains -> 8 edges in flight steady-state.
// Per-node meta is one int4. Epilogue via v_readlane, 4 fma chains.
template <int SAVE_G2>
__global__ __launch_bounds__(256) void spmm_gemm(
    const __hip_bfloat16* __restrict__ G,
    const int4* __restrict__ meta,
    const int* __restrict__ csr_src,
    const float* __restrict__ W,
    __hip_bfloat16* __restrict__ g2,
    float* __restrict__ out, int col_off) {
    __shared__ float wt[D * D];               // wt[k*D + col]
    const int tid = threadIdx.x;
    for (int i = tid; i < D * D; i += 256) wt[i] = W[i];
    __syncthreads();                          // once per block

    const int wv = tid >> 6;
    const int lane = tid & 63;
    const int q = lane >> 4;                  // edge-slot phase 0..3
    const int fp = lane & 15;                 // feature-quad (feats 4fp..4fp+3)
    const uint2* Gp = (const uint2*)G;        // row = 16 uint2 (128 B)
    const int wstride = gridDim.x * 4;        // 8192

    for (int node = blockIdx.x * 4 + wv; node < N_NODES; node += 2 * wstride) {
        const int nodeB = node + wstride;
        const bool hasB = nodeB < N_NODES;
        const int4 mA = meta[node];
        const int4 mB = hasB ? meta[nodeB] : make_int4(0, 0, 0, 0);
        const float nnA = __int_as_float(mA.z);
        const float nnB = __int_as_float(mB.z);

        float aA0 = 0, aA1 = 0, aA2 = 0, aA3 = 0;
        float aB0 = 0, aB1 = 0, aB2 = 0, aB3 = 0;
        const int rA = mA.y >> 2, rB = mB.y >> 2;   // full 4-edge rounds
        int eA = mA.x + q, eB = mB.x + q;
        const int rmin = rA < rB ? rA : rB;
        // interleaved main loop: A and B chains independent
        for (int r = 0; r < rmin; r++) {
            int sA = csr_src[eA];
            int sB = csr_src[eB];
            uint2 pA = Gp[(size_t)sA * 16 + fp];
            uint2 pB = Gp[(size_t)sB * 16 + fp];
            aA0 += __uint_as_float(pA.x << 16);
            aA1 += __uint_as_float(pA.x & 0xffff0000u);
            aA2 += __uint_as_float(pA.y << 16);
            aA3 += __uint_as_float(pA.y & 0xffff0000u);
            aB0 += __uint_as_float(pB.x << 16);
            aB1 += __uint_as_float(pB.x & 0xffff0000u);
            aB2 += __uint_as_float(pB.y << 16);
            aB3 += __uint_as_float(pB.y & 0xffff0000u);
            eA += 4; eB += 4;
        }
        for (int r = rmin; r < rA; r++) {
            int sA = csr_src[eA];
            uint2 pA = Gp[(size_t)sA * 16 + fp];
            aA0 += __uint_as_float(pA.x << 16);
            aA1 += __uint_as_float(pA.x & 0xffff0000u);
            aA2 += __uint_as_float(pA.y << 16);
            aA3 += __uint_as_float(pA.y & 0xffff0000u);
            eA += 4;
        }
        for (int r = rmin; r < rB; r++) {
            int sB = csr_src[eB];
            uint2 pB = Gp[(size_t)sB * 16 + fp];
            aB0 += __uint_as_float(pB.x << 16);
            aB1 += __uint_as_float(pB.x & 0xffff0000u);
            aB2 += __uint_as_float(pB.y << 16);
            aB3 += __uint_as_float(pB.y & 0xffff0000u);
            eB += 4;
        }
        // tails: up to 3 leftover slots, one exec-masked gather each
        if (q < (mA.y & 3)) {
            uint2 p = Gp[(size_t)csr_src[eA] * 16 + fp];
            aA0 += __uint_as_float(p.x << 16);
            aA1 += __uint_as_float(p.x & 0xffff0000u);
            aA2 += __uint_as_float(p.y << 16);
            aA3 += __uint_as_float(p.y & 0xffff0000u);
        }
        if (q < (mB.y & 3)) {
            uint2 p = Gp[(size_t)csr_src[eB] * 16 + fp];
            aB0 += __uint_as_float(p.x << 16);
            aB1 += __uint_as_float(p.x & 0xffff0000u);
            aB2 += __uint_as_float(p.y << 16);
            aB3 += __uint_as_float(p.y & 0xffff0000u);
        }
        // combine the 4 quarters (all lanes end with full sums)
        aA0 += __shfl_xor(aA0, 16); aA0 += __shfl_xor(aA0, 32);
        aA1 += __shfl_xor(aA1, 16); aA1 += __shfl_xor(aA1, 32);
        aA2 += __shfl_xor(aA2, 16); aA2 += __shfl_xor(aA2, 32);
        aA3 += __shfl_xor(aA3, 16); aA3 += __shfl_xor(aA3, 32);
        aB0 += __shfl_xor(aB0, 16); aB0 += __shfl_xor(aB0, 32);
        aB1 += __shfl_xor(aB1, 16); aB1 += __shfl_xor(aB1, 32);
        aB2 += __shfl_xor(aB2, 16); aB2 += __shfl_xor(aB2, 32);
        aB3 += __shfl_xor(aB3, 16); aB3 += __shfl_xor(aB3, 32);
        aA0 *= nnA; aA1 *= nnA; aA2 *= nnA; aA3 *= nnA;   // dst-side norm
        aB0 *= nnB; aB1 *= nnB; aB2 *= nnB; aB3 *= nnB;

        if (SAVE_G2 && q == 0) {              // quarter 0: 16 lanes x 8 B
            __hip_bfloat162 u0, u1;
            u0.x = __float2bfloat16(aA0 * nnA); u0.y = __float2bfloat16(aA1 * nnA);
            u1.x = __float2bfloat16(aA2 * nnA); u1.y = __float2bfloat16(aA3 * nnA);
            ((__hip_bfloat162*)g2)[(size_t)node * 32 + 2 * fp]     = u0;
            ((__hip_bfloat162*)g2)[(size_t)node * 32 + 2 * fp + 1] = u1;
            if (hasB) {
                __hip_bfloat162 v0, v1;
                v0.x = __float2bfloat16(aB0 * nnB); v0.y = __float2bfloat16(aB1 * nnB);
                v1.x = __float2bfloat16(aB2 * nnB); v1.y = __float2bfloat16(aB3 * nnB);
                ((__hip_bfloat162*)g2)[(size_t)nodeB * 32 + 2 * fp]     = v0;
                ((__hip_bfloat162*)g2)[(size_t)nodeB * 32 + 2 * fp + 1] = v1;
            }
        }

        // epilogue A: o[col] = sum_k h[k]*W[k][col]; h[4t+j] lives in lane t
        float o0 = 0, o1 = 0, o2 = 0, o3 = 0;
#pragma unroll
        for (int t = 0; t < 16; t++) {
            o0 = fmaf(__uint_as_float(__builtin_amdgcn_readlane(__float_as_uint(aA0), t)),
                      wt[(4 * t + 0) * D + lane], o0);
            o1 = fmaf(__uint_as_float(__builtin_amdgcn_readlane(__float_as_uint(aA1), t)),
                      wt[(4 * t + 1) * D + lane], o1);
            o2 = fmaf(__uint_as_float(__builtin_amdgcn_readlane(__float_as_uint(aA2), t)),
                      wt[(4 * t + 2) * D + lane], o2);
            o3 = fmaf(__uint_as_float(__builtin_amdgcn_readlane(__float_as_uint(aA3), t)),
                      wt[(4 * t + 3) * D + lane], o3);
        }
        out[(size_t)node * 192 + col_off + lane] = (o0 + o1) + (o2 + o3);

        if (hasB) {
            float p0 = 0, p1 = 0, p2 = 0, p3 = 0;
#pragma unroll
            for (int t = 0; t < 16; t++) {
                p0 = fmaf(__uint_as_float(__builtin_amdgcn_readlane(__float_as_uint(aB0), t)),
                          wt[(4 * t + 0) * D + lane], p0);
                p1 = fmaf(__uint_as_float(__builtin_amdgcn_readlane(__float_as_uint(aB1), t)),
                          wt[(4 * t + 1) * D + lane], p1);
                p2 = fmaf(__uint_as_float(__builtin_amdgcn_readlane(__float_as_uint(aB2), t)),
                          wt[(4 * t + 2) * D + lane], p2);
                p3 = fmaf(__uint_as_float(__builtin_amdgcn_readlane(__float_as_uint(aB3), t)),
                          wt[(4 * t + 3) * D + lane], p3);
            }
            out[(size_t)nodeB * 192 + col_off + lane] = (p0 + p1) + (p2 + p3);
        }
    }
}

extern "C" void kernel_launch(void* const* d_in, const int* in_sizes, int n_in,
                              void* d_out, int out_size, void* d_ws, size_t ws_size,
                              hipStream_t stream) {
    const float* feats = (const float*)d_in[0];
    const float* ew    = (const float*)d_in[1];
    const float* w0    = (const float*)d_in[2];
    const float* w1    = (const float*)d_in[3];
    const float* w2    = (const float*)d_in[4];
    const int* src   = (const int*)d_in[5];
    const int* dst   = (const int*)d_in[6];
    const int* efeat = (const int*)d_in[7];
    float* out = (float*)d_out;

    // ws layout (~32 MiB): dc[N] u64 (800000 B) | total (16 B) |
    // meta[N] int4 (1.6 MB) | csr_src[1M] (4 MB) | g1 (12.8 MB) | g2 (12.8 MB)
    // rank[1M u8] ALIASES g2: hist writes rank, fill reads it, then spmm<1>
    // overwrites g2 — strictly ordered on the stream.
    unsigned long long* dc = (unsigned long long*)d_ws;
    int* total     = (int*)(dc + N_NODES);
    int4* meta     = (int4*)((char*)total + 16);
    int* csr_src   = (int*)(meta + N_NODES);
    __hip_bfloat16* g1 = (__hip_bfloat16*)(csr_src + N_EDGES);
    __hip_bfloat16* g2 = g1 + (size_t)N_NODES * D;
    unsigned char* rank = (unsigned char*)g2;  // dead before spmm<1> runs

    // zero dc + total only (~800 KB)
    hipMemsetAsync(d_ws, 0, sizeof(unsigned long long) * N_NODES + 16, stream);

    hist_kernel<<<(N_EDGES / 4 + 255) / 256, 256, 0, stream>>>(
        dst, efeat, ew, dc, rank);
    alloc_prep_kernel<<<(N_NODES + 255) / 256, 256, 0, stream>>>(
        dc, feats, meta, total, g1);
    fill_kernel<<<(N_EDGES / 4 + 255) / 256, 256, 0, stream>>>(
        src, dst, rank, (const int*)meta, csr_src);
    gemm_kernel<<<(N_NODES + 31) / 32, 256, 0, stream>>>(feats, w0, out);

    // cols 64..127 = (norm ⊙ A g1) @ W1, saving g2 = bf16(norm² ⊙ A g1)
    spmm_gemm<1><<<2048, 256, 0, stream>>>(
        g1, meta, csr_src, w1, g2, out, 64);
    // cols 128..191 = (norm ⊙ A g2) @ W2
    spmm_gemm<0><<<2048, 256, 0, stream>>>(
        g2, meta, csr_src, w2, nullptr, out, 128);
}